// Round 1
// baseline (665.170 us; speedup 1.0000x reference)
//
#include <hip/hip_runtime.h>
#include <cstdint>

// ---- types ----
typedef short bf16x8 __attribute__((ext_vector_type(8)));        // 8 bf16 in 4 VGPRs
typedef unsigned short u16x8 __attribute__((ext_vector_type(8)));
typedef float f32x4 __attribute__((ext_vector_type(4)));
typedef __attribute__((address_space(3))) uint32_t lds_u32;
typedef const __attribute__((address_space(1))) uint32_t gbl_u32;

// fp32 -> bf16 bits, round-to-nearest-even
__device__ __forceinline__ unsigned short f2bf(float f) {
  union { float f; uint32_t u; } c; c.f = f;
  uint32_t u = c.u;
  return (unsigned short)((u + 0x7fffu + ((u >> 16) & 1u)) >> 16);
}

// ---- x fp32 -> bf16, 8 elems/thread ----
__global__ void cvt_x_kernel(const float* __restrict__ x,
                             unsigned short* __restrict__ y, long n) {
  long t = (long)blockIdx.x * blockDim.x + threadIdx.x;
  long base = t * 8;
  if (base >= n) return;
  const float4* p = (const float4*)(x + base);
  float4 f0 = p[0], f1 = p[1];
  u16x8 v;
  v[0] = f2bf(f0.x); v[1] = f2bf(f0.y); v[2] = f2bf(f0.z); v[3] = f2bf(f0.w);
  v[4] = f2bf(f1.x); v[5] = f2bf(f1.y); v[6] = f2bf(f1.z); v[7] = f2bf(f1.w);
  *(u16x8*)(y + base) = v;
}

// ---- W dequant: bf16(lut[idx] * scale), 8 elems/thread ----
__global__ void dequant_kernel(const int* __restrict__ idx,
                               const float* __restrict__ lut,
                               const float* __restrict__ scale,
                               unsigned short* __restrict__ w, long n) {
  __shared__ unsigned short slut[16];
  if (threadIdx.x < 15) slut[threadIdx.x] = f2bf(lut[threadIdx.x] * scale[0]);
  __syncthreads();
  long t = (long)blockIdx.x * blockDim.x + threadIdx.x;
  long base = t * 8;
  if (base >= n) return;
  const int4* p = (const int4*)(idx + base);
  int4 i0 = p[0], i1 = p[1];
  u16x8 v;
  v[0] = slut[i0.x]; v[1] = slut[i0.y]; v[2] = slut[i0.z]; v[3] = slut[i0.w];
  v[4] = slut[i1.x]; v[5] = slut[i1.y]; v[6] = slut[i1.z]; v[7] = slut[i1.w];
  *(u16x8*)(w + base) = v;
}

// ---- bf16 NT-GEMM: C[M][N] = A[M][K] * B[N][K]^T, m97-ladder structure ----
// 128x128 block tile, BK=32, 256 threads = 4 waves in 2x2, each wave 4x4 of
// 16x16x32 MFMA. LDS tiles are unpadded row-major [128][32] bf16 so that
// global_load_lds's wave-uniform-base + lane*16 destination matches exactly.
__global__ __launch_bounds__(256) void gemm_bt(
    const unsigned short* __restrict__ A,   // [M][K] bf16 bits
    const unsigned short* __restrict__ B,   // [N][K] bf16 bits
    float* __restrict__ C, int M, int N, int K) {
  __shared__ unsigned short lA[128 * 32];
  __shared__ unsigned short lB[128 * 32];

  const int t = threadIdx.x;
  const int l = t & 63;
  const int w = t >> 6;
  const int wm = w >> 1, wn = w & 1;
  const int bm = blockIdx.y, bn = blockIdx.x;

  f32x4 acc[4][4] = {};

  // Staging: issue p in {0,1}: row = p*64 + (t>>2), colChunk = (t&3)*8.
  // LDS byte offset = row*64 + (t&3)*16 = p*4096 + waveBase + lane*16. (contiguous)
  const unsigned short* gA = A + (size_t)(bm * 128 + (t >> 2)) * K + (t & 3) * 8;
  const unsigned short* gB = B + (size_t)(bn * 128 + (t >> 2)) * K + (t & 3) * 8;
  lds_u32* sA = (lds_u32*)(&lA[0]) + t * 4;
  lds_u32* sB = (lds_u32*)(&lB[0]) + t * 4;

  const int ar = wm * 64 + (l & 15);
  const int br = wn * 64 + (l & 15);
  const int ak = (l >> 4) * 8;

  for (int kt = 0; kt < K; kt += 32) {
    __syncthreads();  // previous iteration's LDS reads complete
    __builtin_amdgcn_global_load_lds((gbl_u32*)(gA + kt),          sA,        16, 0, 0);
    __builtin_amdgcn_global_load_lds((gbl_u32*)(gA + 64 * K + kt), sA + 1024, 16, 0, 0);
    __builtin_amdgcn_global_load_lds((gbl_u32*)(gB + kt),          sB,        16, 0, 0);
    __builtin_amdgcn_global_load_lds((gbl_u32*)(gB + 64 * K + kt), sB + 1024, 16, 0, 0);
    __syncthreads();  // drains vmcnt(0) then barrier

    bf16x8 af[4], bfr[4];
#pragma unroll
    for (int i = 0; i < 4; ++i)
      af[i] = *(const bf16x8*)&lA[(ar + i * 16) * 32 + ak];
#pragma unroll
    for (int j = 0; j < 4; ++j)
      bfr[j] = *(const bf16x8*)&lB[(br + j * 16) * 32 + ak];
#pragma unroll
    for (int i = 0; i < 4; ++i)
#pragma unroll
      for (int j = 0; j < 4; ++j)
        acc[i][j] = __builtin_amdgcn_mfma_f32_16x16x32_bf16(af[i], bfr[j], acc[i][j], 0, 0, 0);
  }

  // Epilogue: C/D layout col=lane&15, row=(lane>>4)*4+reg (m89/m91-verified)
  float* Cp = C + (size_t)(bm * 128 + wm * 64 + (l >> 4) * 4) * N
              + bn * 128 + wn * 64 + (l & 15);
#pragma unroll
  for (int i = 0; i < 4; ++i)
#pragma unroll
    for (int j = 0; j < 4; ++j)
#pragma unroll
      for (int r = 0; r < 4; ++r)
        Cp[(size_t)(i * 16 + r) * N + j * 16] = acc[i][j][r];
}

extern "C" void kernel_launch(void* const* d_in, const int* in_sizes, int n_in,
                              void* d_out, int out_size, void* d_ws, size_t ws_size,
                              hipStream_t stream) {
  const float* x     = (const float*)d_in[0];   // [4,2048,2048] fp32
  const int*   gi    = (const int*)d_in[1];     // [8192,2048] int32
  const float* scale = (const float*)d_in[2];   // scalar
  const float* lut   = (const float*)d_in[3];   // [15] fp32
  float* out = (float*)d_out;                   // [4,2048,8192] fp32

  const int M = 8192, N = 8192, K = 2048;
  unsigned short* xb = (unsigned short*)d_ws;          // 32 MiB bf16 x
  unsigned short* wb = xb + (size_t)M * K;             // 32 MiB bf16 W

  long nx = (long)M * K;
  long nw = (long)N * K;
  cvt_x_kernel<<<dim3((unsigned)(nx / (256 * 8))), dim3(256), 0, stream>>>(x, xb, nx);
  dequant_kernel<<<dim3((unsigned)(nw / (256 * 8))), dim3(256), 0, stream>>>(gi, lut, scale, wb, nw);

  dim3 grid(N / 128, M / 128);
  gemm_bt<<<grid, dim3(256), 0, stream>>>(xb, wb, out, M, N, K);
}